// Round 12
// baseline (368.865 us; speedup 1.0000x reference)
//
#include <hip/hip_runtime.h>

#define K3 27
#define CENTER 13
#define NC 32
#define NREP 32   // histogram replicas (replica-major planes)

// ---------------------------------------------------------------------------
// conv1: 128-pt LDS tile, thread owns ONE point x 16 out-ch (2 thr/point).
// Halves ds_read traffic vs 8-ch/thread (FMA per b128 = 4*outch = 64).
// W wave-uniform via t>>7 (waves 0-1: ch 0-15, waves 2-3: ch 16-31).
// ---------------------------------------------------------------------------
__global__ __launch_bounds__(256) void conv1_kernel(
    const float* __restrict__ xF,
    const float* __restrict__ Wch,
    const float* __restrict__ bch,
    const int*   __restrict__ nbr,
    float*  __restrict__ xo,
    double* __restrict__ so,
    double* __restrict__ cno)
{
    __shared__ float Gs[2][128 * 32];      // 2 x 16 KB
    const int t     = threadIdx.x;
    const int pbase = blockIdx.x << 7;     // 128 points/block
    const int g16   = __builtin_amdgcn_readfirstlane(t >> 7);  // ch half, wave-uniform
    const int p     = t & 127;
    const int sw    = p & 7;
    const int srow  = t >> 1;              // staging row (2 threads/row)
    const int sh    = t & 1;
    const int stsw  = srow & 7;

    float acc[16];
#pragma unroll
    for (int d = 0; d < 16; d++) acc[d] = 0.f;

    float4 stg[4];
    {
        const int j = nbr[(size_t)(pbase + srow) * K3];
        if (j >= 0) {
            const float4* src = (const float4*)(xF + (size_t)j * NC) + sh * 4;
#pragma unroll
            for (int m = 0; m < 4; m++) stg[m] = src[m];
        } else {
            const float4 z = make_float4(0.f, 0.f, 0.f, 0.f);
#pragma unroll
            for (int m = 0; m < 4; m++) stg[m] = z;
        }
    }

    for (int k = 0; k < K3; k++) {
        const int cur = k & 1;
        {
            float4* dst = (float4*)(Gs[cur] + srow * 32);
#pragma unroll
            for (int m = 0; m < 4; m++) dst[(4 * sh + m) ^ stsw] = stg[m];
        }
        __syncthreads();
        if (k + 1 < K3) {
            const int j = nbr[(size_t)(pbase + srow) * K3 + k + 1];
            if (j >= 0) {
                const float4* src = (const float4*)(xF + (size_t)j * NC) + sh * 4;
#pragma unroll
                for (int m = 0; m < 4; m++) stg[m] = src[m];
            } else {
                const float4 z = make_float4(0.f, 0.f, 0.f, 0.f);
#pragma unroll
                for (int m = 0; m < 4; m++) stg[m] = z;
            }
        }
        const float* __restrict__ Wk = Wch + k * (NC * NC) + g16 * 16;
#pragma unroll
        for (int cc = 0; cc < 8; ++cc) {
            const float4 g0 = ((const float4*)(Gs[cur] + p * 32))[cc ^ sw];
#pragma unroll
            for (int c4 = 0; c4 < 4; c4++) {
                const float gc = (c4 == 0) ? g0.x : (c4 == 1) ? g0.y : (c4 == 2) ? g0.z : g0.w;
                const float4* wr = (const float4*)(Wk + (cc * 4 + c4) * NC);
#pragma unroll
                for (int d4 = 0; d4 < 4; d4++) {
                    const float4 w = wr[d4];
                    acc[d4 * 4 + 0] = fmaf(gc, w.x, acc[d4 * 4 + 0]);
                    acc[d4 * 4 + 1] = fmaf(gc, w.y, acc[d4 * 4 + 1]);
                    acc[d4 * 4 + 2] = fmaf(gc, w.z, acc[d4 * 4 + 2]);
                    acc[d4 * 4 + 3] = fmaf(gc, w.w, acc[d4 * 4 + 3]);
                }
            }
        }
        __syncthreads();
    }

    // bias (uniform scalar loads)
#pragma unroll
    for (int d = 0; d < 16; d++) acc[d] += bch[g16 * 16 + d];
    // park acc in Gs[0] (swizzled: logical chunk c = g16*4+j at slot c^sw)
    {
        float4* dst = (float4*)(Gs[0] + p * 32);
#pragma unroll
        for (int j = 0; j < 4; j++)
            dst[(g16 * 4 + j) ^ sw] =
                make_float4(acc[4 * j], acc[4 * j + 1], acc[4 * j + 2], acc[4 * j + 3]);
    }
    __syncthreads();
    if (t < 128) {
        double sum = 0.0, sq = 0.0;
        const float4* row = (const float4*)(Gs[0] + t * 32);
        const int tsw = t & 7;
#pragma unroll
        for (int m = 0; m < 8; m++) {
            const float4 v = row[m ^ tsw];
            sum += (double)v.x + (double)v.y + (double)v.z + (double)v.w;
            sq  += (double)v.x * v.x + (double)v.y * v.y + (double)v.z * v.z + (double)v.w * v.w;
        }
        so[pbase + t]  = sum;
        cno[pbase + t] = sq;
    }
    {
        float4* xout = (float4*)(xo + (size_t)pbase * NC);
#pragma unroll
        for (int f = 0; f < 4; f++) {
            const int idx = f * 256 + t;
            const int row = idx >> 3;
            const int m   = idx & 7;
            xout[idx] = ((const float4*)(Gs[0] + row * 32))[m ^ (row & 7)];
        }
    }
}

// ---------------------------------------------------------------------------
// corr + replicated histogram: 4 threads/point (64 pts per 256-thr block,
// grid N/64 = 2048 -> 8 blocks/CU, full occupancy). Each thread gathers <=7
// taps; shfl_xor double reduce; lane sub==0 finalizes.
// ---------------------------------------------------------------------------
__global__ __launch_bounds__(256) void corr_hist_kernel(
    const double* __restrict__ s,
    const double* __restrict__ cn,
    const int*    __restrict__ nbr,
    unsigned*     __restrict__ key,
    unsigned*     __restrict__ rep,
    int NBpts, int N)
{
    const int t   = threadIdx.x;
    const int sub = t & 3;
    const int n   = blockIdx.x * 64 + (t >> 2);
    const int k0  = sub * 7;
    const int k1  = (k0 + 7 < K3) ? (k0 + 7) : K3;   // 7,7,7,6 taps
    const int* __restrict__ nrow = nbr + (size_t)n * K3;

    int jj[7];
#pragma unroll
    for (int i = 0; i < 7; i++) {
        const int k = k0 + i;
        jj[i] = (k < k1 && k != CENTER) ? nrow[k] : -1;
    }
    double v[7];
#pragma unroll
    for (int i = 0; i < 7; i++) {
        const int j = jj[i];
        const double val = s[(j < 0) ? 0 : j];   // unconditional load -> MLP
        v[i] = (j < 0) ? 0.0 : val;
    }
    double part = ((v[0] + v[1]) + (v[2] + v[3])) + ((v[4] + v[5]) + v[6]);
    part += __shfl_xor(part, 1);
    part += __shfl_xor(part, 2);
    if (sub == 0) {
        const float corr = (float)(part / cn[n]);
        const unsigned uu = __float_as_uint(corr);
        const unsigned u  = (uu & 0x80000000u) ? ~uu : (uu | 0x80000000u);
        key[n] = u;
        const int b = n / NBpts;
        const unsigned r = (unsigned)blockIdx.x & (NREP - 1);
        atomicAdd(&rep[(size_t)r * (2u * 65536u) + (size_t)b * 65536u + (u >> 16)], 1u);
    }
}

// ---------------------------------------------------------------------------
__global__ __launch_bounds__(256) void reduce_rep_kernel(
    const unsigned* __restrict__ rep,
    unsigned*       __restrict__ hist_sum)
{
    const int g = blockIdx.x * 256 + threadIdx.x;
    unsigned sum = 0;
#pragma unroll
    for (int r = 0; r < NREP; r++)
        sum += rep[(size_t)r * (2u * 65536u) + g];
    hist_sum[g] = sum;
}

// ---------------------------------------------------------------------------
__global__ __launch_bounds__(1024) void scan_hi_kernel(
    const unsigned* __restrict__ hist,
    const int*      __restrict__ thp,
    unsigned*       __restrict__ selhi,
    int*            __restrict__ selrk,
    int NBpts)
{
    __shared__ unsigned ss[1024];
    const int b = blockIdx.x;
    const int t = threadIdx.x;
    const unsigned* h = hist + (size_t)b * 65536u + t * 64;
    unsigned sum = 0;
#pragma unroll 8
    for (int i = 0; i < 64; i++) sum += h[i];
    ss[t] = sum;
    __syncthreads();
    for (int off = 1; off < 1024; off <<= 1) {
        unsigned v = (t + off < 1024) ? ss[t + off] : 0u;
        __syncthreads();
        ss[t] += v;
        __syncthreads();
    }
    int k = (int)((double)NBpts * (double)thp[0] / 3.21);
    if (k < 1) k = 1;
    if (k > NBpts) k = NBpts;
    unsigned run = ss[t] - sum;
    for (int i = 63; i >= 0; --i) {
        const unsigned c = h[i];
        if ((int)run < k && k <= (int)(run + c)) {
            selhi[b] = (unsigned)(t * 64 + i);
            selrk[b] = k - (int)run;
        }
        run += c;
    }
}

// ---------------------------------------------------------------------------
__global__ __launch_bounds__(256) void hist_lo_kernel(
    const unsigned* __restrict__ key,
    const unsigned* __restrict__ selhi,
    unsigned*       __restrict__ hist2,
    int NBpts, int N)
{
    const int n = blockIdx.x * 256 + threadIdx.x;
    if (n >= N) return;
    const int b = n / NBpts;
    const unsigned u = key[n];
    if ((u >> 16) == selhi[b])
        atomicAdd(&hist2[(size_t)b * 65536u + (u & 0xFFFFu)], 1u);
}

// ---------------------------------------------------------------------------
__global__ __launch_bounds__(1024) void scan_lo_kernel(
    const unsigned* __restrict__ hist2,
    const unsigned* __restrict__ selhi,
    const int*      __restrict__ selrk,
    unsigned*       __restrict__ selT,
    int*            __restrict__ selr)
{
    __shared__ unsigned ss[1024];
    const int b = blockIdx.x;
    const int t = threadIdx.x;
    const unsigned* h = hist2 + (size_t)b * 65536u + t * 64;
    unsigned sum = 0;
#pragma unroll 8
    for (int i = 0; i < 64; i++) sum += h[i];
    ss[t] = sum;
    __syncthreads();
    for (int off = 1; off < 1024; off <<= 1) {
        unsigned v = (t + off < 1024) ? ss[t + off] : 0u;
        __syncthreads();
        ss[t] += v;
        __syncthreads();
    }
    const int k = selrk[b];
    unsigned run = ss[t] - sum;
    for (int i = 63; i >= 0; --i) {
        const unsigned c = h[i];
        if ((int)run < k && k <= (int)(run + c)) {
            selT[b] = (selhi[b] << 16) | (unsigned)(t * 64 + i);
            selr[b] = k - (int)run;
        }
        run += c;
    }
}

// ---------------------------------------------------------------------------
__global__ __launch_bounds__(256) void mask_kernel(
    const unsigned* __restrict__ key,
    const unsigned* __restrict__ selT,
    int* __restrict__ mask,
    int* __restrict__ eqcnt,
    int NBpts)
{
    __shared__ int wc[4];
    const int n = blockIdx.x * 256 + threadIdx.x;
    const int b = n / NBpts;
    const unsigned u = key[n];
    const unsigned T = selT[b];
    mask[n] = (u > T) ? 1 : 0;
    const unsigned long long bal = __ballot(u == T);
    const int lane = threadIdx.x & 63;
    const int wid  = threadIdx.x >> 6;
    if (lane == 0) wc[wid] = __popcll(bal);
    __syncthreads();
    if (threadIdx.x == 0) eqcnt[blockIdx.x] = wc[0] + wc[1] + wc[2] + wc[3];
}

__global__ __launch_bounds__(512) void scan_kernel(
    const int* __restrict__ in, int* __restrict__ out,
    int n, int seg, int* __restrict__ total)
{
    __shared__ int ss[512];
    const int t = threadIdx.x;
    const int v = (t < n) ? in[t] : 0;
    ss[t] = v;
    __syncthreads();
    for (int off = 1; off < seg; off <<= 1) {
        int a = ((t & (seg - 1)) >= off) ? ss[t - off] : 0;
        __syncthreads();
        ss[t] += a;
        __syncthreads();
    }
    if (t < n) out[t] = ss[t] - v;
    if (total != nullptr && t == n - 1) total[0] = ss[t];
}

__global__ __launch_bounds__(256) void eqfinal_kernel(
    const unsigned* __restrict__ key,
    const unsigned* __restrict__ selT,
    const int*      __restrict__ selr,
    const int*      __restrict__ eqoff,
    int* __restrict__ mask,
    int* __restrict__ mcnt,
    int NBpts)
{
    __shared__ int wc[4], wm[4];
    const int n = blockIdx.x * 256 + threadIdx.x;
    const int b = n / NBpts;
    const unsigned u = key[n];
    const unsigned T = selT[b];
    const bool gt = (u > T);
    const bool eq = (u == T);
    const unsigned long long bal = __ballot(eq);
    const int lane = threadIdx.x & 63;
    const int wid  = threadIdx.x >> 6;
    if (lane == 0) wc[wid] = __popcll(bal);
    __syncthreads();
    int base = eqoff[blockIdx.x];
    for (int w = 0; w < wid; w++) base += wc[w];
    bool keep = false;
    if (eq) {
        const int g = base + __popcll(bal & ((1ull << lane) - 1ull));
        keep = (g < selr[b]);
        if (keep) mask[n] = 1;
    }
    const unsigned long long balm = __ballot(gt || keep);
    if (lane == 0) wm[wid] = __popcll(balm);
    __syncthreads();
    if (threadIdx.x == 0) mcnt[blockIdx.x] = wm[0] + wm[1] + wm[2] + wm[3];
}

__global__ __launch_bounds__(256) void emit_kernel(
    const int* __restrict__ mask,
    const int* __restrict__ moff,
    int* __restrict__ list)
{
    __shared__ int wc[4];
    const int n = blockIdx.x * 256 + threadIdx.x;
    const bool m = mask[n] != 0;
    const unsigned long long bal = __ballot(m);
    const int lane = threadIdx.x & 63;
    const int wid  = threadIdx.x >> 6;
    if (lane == 0) wc[wid] = __popcll(bal);
    __syncthreads();
    int base = moff[blockIdx.x];
    for (int w = 0; w < wid; w++) base += wc[w];
    if (m) list[base + __popcll(bal & ((1ull << lane) - 1ull))] = n;
}

// ---------------------------------------------------------------------------
__global__ __launch_bounds__(256) void scale2_kernel(
    const float4* __restrict__ x, float4* __restrict__ out, int n4)
{
    const int i = blockIdx.x * 256 + threadIdx.x;
    if (i < n4) {
        const float4 v = x[i];
        out[i] = make_float4(v.x + v.x, v.y + v.y, v.z + v.z, v.w + v.w);
    }
}

// ---------------------------------------------------------------------------
// conv2: same 16-ch/thread 128-pt structure; points from ordered list,
// gathers gated by valid & mask. out[p] = conv + b_dw + x[p].
// ---------------------------------------------------------------------------
__global__ __launch_bounds__(256) void conv2_kernel(
    const float* __restrict__ x,
    const float* __restrict__ Wdw,
    const float* __restrict__ bdw,
    const int*   __restrict__ nbr,
    const int*   __restrict__ mask,
    const int*   __restrict__ list,
    const int*   __restrict__ cnt,
    float* __restrict__ out)
{
    __shared__ float Gs[2][128 * 32];
    const int t     = threadIdx.x;
    const int base  = blockIdx.x << 7;
    const int count = *cnt;
    if (base >= count) return;              // block-uniform early exit
    const int g16   = __builtin_amdgcn_readfirstlane(t >> 7);
    const int p     = t & 127;
    const int sw    = p & 7;
    const int srow  = t >> 1;
    const int sh    = t & 1;
    const int stsw  = srow & 7;
    const int sp    = (base + srow < count) ? list[base + srow] : -1;

    float acc[16];
#pragma unroll
    for (int d = 0; d < 16; d++) acc[d] = 0.f;

    float4 stg[4];
    {
        const int j = (sp >= 0) ? nbr[(size_t)sp * K3] : -1;
        const bool v = (j >= 0) && (mask[j] != 0);
        if (v) {
            const float4* src = (const float4*)(x + (size_t)j * NC) + sh * 4;
#pragma unroll
            for (int m = 0; m < 4; m++) stg[m] = src[m];
        } else {
            const float4 z = make_float4(0.f, 0.f, 0.f, 0.f);
#pragma unroll
            for (int m = 0; m < 4; m++) stg[m] = z;
        }
    }

    for (int k = 0; k < K3; k++) {
        const int cur = k & 1;
        {
            float4* dst = (float4*)(Gs[cur] + srow * 32);
#pragma unroll
            for (int m = 0; m < 4; m++) dst[(4 * sh + m) ^ stsw] = stg[m];
        }
        __syncthreads();
        if (k + 1 < K3) {
            const int j = (sp >= 0) ? nbr[(size_t)sp * K3 + k + 1] : -1;
            const bool v = (j >= 0) && (mask[j] != 0);
            if (v) {
                const float4* src = (const float4*)(x + (size_t)j * NC) + sh * 4;
#pragma unroll
                for (int m = 0; m < 4; m++) stg[m] = src[m];
            } else {
                const float4 z = make_float4(0.f, 0.f, 0.f, 0.f);
#pragma unroll
                for (int m = 0; m < 4; m++) stg[m] = z;
            }
        }
        const float* __restrict__ Wk = Wdw + k * (NC * NC) + g16 * 16;
#pragma unroll
        for (int cc = 0; cc < 8; ++cc) {
            const float4 g0 = ((const float4*)(Gs[cur] + p * 32))[cc ^ sw];
#pragma unroll
            for (int c4 = 0; c4 < 4; c4++) {
                const float gc = (c4 == 0) ? g0.x : (c4 == 1) ? g0.y : (c4 == 2) ? g0.z : g0.w;
                const float4* wr = (const float4*)(Wk + (cc * 4 + c4) * NC);
#pragma unroll
                for (int d4 = 0; d4 < 4; d4++) {
                    const float4 w = wr[d4];
                    acc[d4 * 4 + 0] = fmaf(gc, w.x, acc[d4 * 4 + 0]);
                    acc[d4 * 4 + 1] = fmaf(gc, w.y, acc[d4 * 4 + 1]);
                    acc[d4 * 4 + 2] = fmaf(gc, w.z, acc[d4 * 4 + 2]);
                    acc[d4 * 4 + 3] = fmaf(gc, w.w, acc[d4 * 4 + 3]);
                }
            }
        }
        __syncthreads();
    }

    {
        float4* dst = (float4*)(Gs[0] + p * 32);
#pragma unroll
        for (int j = 0; j < 4; j++)
            dst[(g16 * 4 + j) ^ sw] =
                make_float4(acc[4 * j], acc[4 * j + 1], acc[4 * j + 2], acc[4 * j + 3]);
    }
    __syncthreads();
    if (t < 128) {
        const int pt = (base + t < count) ? list[base + t] : -1;
        if (pt >= 0) {
            const float4* row = (const float4*)(Gs[0] + t * 32);
            const float4* xr  = (const float4*)(x + (size_t)pt * NC);
            const float4* bb  = (const float4*)bdw;
            float4* orow = (float4*)(out + (size_t)pt * NC);
            const int tsw = t & 7;
#pragma unroll
            for (int m = 0; m < 8; m++) {
                const float4 a  = row[m ^ tsw];
                const float4 bv = bb[m];
                const float4 xv = xr[m];
                orow[m] = make_float4((a.x + bv.x) + xv.x, (a.y + bv.y) + xv.y,
                                      (a.z + bv.z) + xv.z, (a.w + bv.w) + xv.w);
            }
        }
    }
}

// ---------------------------------------------------------------------------
extern "C" void kernel_launch(void* const* d_in, const int* in_sizes, int n_in,
                              void* d_out, int out_size, void* d_ws, size_t ws_size,
                              hipStream_t stream)
{
    const float* xF  = (const float*)d_in[0];
    const float* Wch = (const float*)d_in[1];
    const float* bch = (const float*)d_in[2];
    const float* Wdw = (const float*)d_in[3];
    const float* bdw = (const float*)d_in[4];
    const int*   nbr = (const int*)d_in[5];
    const int*   thp = (const int*)d_in[6];

    const int N = in_sizes[0] / NC;   // 131072
    const int NBpts = N / 2;          // 65536 per batch
    float* out = (float*)d_out;

    char* ws = (char*)d_ws;
    size_t off = 0;
    float*    x     = (float*)(ws + off);    off += (size_t)N * NC * sizeof(float);
    double*   s     = (double*)(ws + off);   off += (size_t)N * sizeof(double);
    double*   cn    = (double*)(ws + off);   off += (size_t)N * sizeof(double);
    unsigned* key   = (unsigned*)(ws + off); off += (size_t)N * sizeof(unsigned);
    int*      mask  = (int*)(ws + off);      off += (size_t)N * sizeof(int);
    int*      list  = (int*)(ws + off);      off += (size_t)N * sizeof(int);
    unsigned* hsum  = (unsigned*)(ws + off); off += 2u * 65536u * sizeof(unsigned);
    unsigned* hist2 = (unsigned*)(ws + off); off += 2u * 65536u * sizeof(unsigned);
    const size_t zero_bytes = 2u * 65536u * sizeof(unsigned);
    int*      cnt   = (int*)(ws + off);      off += 256;
    unsigned* selhi = (unsigned*)(ws + off); off += 256;
    int*      selrk = (int*)(ws + off);      off += 256;
    unsigned* selT  = (unsigned*)(ws + off); off += 256;
    int*      selr  = (int*)(ws + off);      off += 256;
    int*      eqcnt = (int*)(ws + off);      off += 512 * sizeof(int);
    int*      eqoff = (int*)(ws + off);      off += 512 * sizeof(int);
    int*      mcnt  = (int*)(ws + off);      off += 512 * sizeof(int);
    int*      moff  = (int*)(ws + off);      off += 512 * sizeof(int);

    const int nblk  = N / 256;  // 512 (selection kernels)
    const int cblk  = N / 128;  // 1024 (conv kernels)
    const int hblk  = N / 64;   // 2048 (corr_hist, 4 thr/point)

    // d_out doubles as the replica-major histogram scratch; scale2 overwrites.
    unsigned* rep = (unsigned*)d_out;

    hipMemsetAsync(rep, 0, (size_t)out_size * sizeof(float), stream);
    hipMemsetAsync(hist2, 0, zero_bytes, stream);
    conv1_kernel<<<cblk, 256, 0, stream>>>(xF, Wch, bch, nbr, x, s, cn);
    corr_hist_kernel<<<hblk, 256, 0, stream>>>(s, cn, nbr, key, rep, NBpts, N);
    reduce_rep_kernel<<<nblk, 256, 0, stream>>>(rep, hsum);
    scan_hi_kernel<<<2, 1024, 0, stream>>>(hsum, thp, selhi, selrk, NBpts);
    hist_lo_kernel<<<nblk, 256, 0, stream>>>(key, selhi, hist2, NBpts, N);
    scan_lo_kernel<<<2, 1024, 0, stream>>>(hist2, selhi, selrk, selT, selr);
    mask_kernel<<<nblk, 256, 0, stream>>>(key, selT, mask, eqcnt, NBpts);
    scan_kernel<<<1, 512, 0, stream>>>(eqcnt, eqoff, nblk, 256, nullptr);
    eqfinal_kernel<<<nblk, 256, 0, stream>>>(key, selT, selr, eqoff, mask, mcnt, NBpts);
    scan_kernel<<<1, 512, 0, stream>>>(mcnt, moff, nblk, 512, cnt);
    emit_kernel<<<nblk, 256, 0, stream>>>(mask, moff, list);
    scale2_kernel<<<(N * NC / 4) / 256, 256, 0, stream>>>((const float4*)x, (float4*)out, N * NC / 4);
    conv2_kernel<<<cblk, 256, 0, stream>>>(x, Wdw, bdw, nbr, mask, list, cnt, out);
}